// Round 7
// baseline (4516.058 us; speedup 1.0000x reference)
//
#include <hip/hip_runtime.h>
#include <hip/hip_fp16.h>
#include <math.h>

// BatchSpectralLoss: out = lambda_max(A^T A), A = 8192x4096 fp32 (k==1).
// PERSISTENT single-kernel Lanczos (T=16), 512 blocks x 256 thr, 2 blocks/CU.
// A converted once to fp16 in ws (each block converts its own 16-row slice);
// per step the block re-reads its slice from L2/L3 in 4-row batches (32 VGPRs
// held -> no spill, unlike R6's 128-VGPR register-residency attempt).
// No contended atomics anywhere: alpha = redundant reduce of su[8192],
// norm2 = redundant reduce of n2part[512]. Grid sync = 2-level barrier
// (16-block groups -> root), 2 per step. Sturm bisection in block 0.
//
// ws float layout: vb0@0 vb1@4096 vb2@8192 | slots@12288 (128)
//   su@12544 (8192) | bar@20736 (64 u32) | n2part@20800 (512)
//   partials@24576 (512x4096) | Ah (fp16) @ byte offset 16 MiB (64 MB)

#define NROWS 8192
#define NCOLS 4096
#define T_STEPS 16
#define GRID 512
#define RPB 16
#define BATCH 4

__global__ __launch_bounds__(256) void init_kernel(float* __restrict__ ws) {
    int i = blockIdx.x * 256 + threadIdx.x;   // 0..4095
    unsigned h = (unsigned)i * 2654435761u;
    h ^= h >> 16; h *= 2246822519u; h ^= h >> 13;
    ws[4096 + i] = (h & 1u) ? 0.015625f : -0.015625f;  // vb1 = r1 (unit norm)
    ws[i] = 0.f;                                        // vb0 = r0 = 0
    if (i < 128) ws[12288 + i] = (i == 64 || i == 65) ? 1.f : 0.f;  // slots
    if (i < 64) ((unsigned*)(ws + 20736))[i] = 0u;      // barrier counters
    if (i < 512) ws[20800 + i] = 0.f;                   // n2part
}

__device__ __forceinline__ void gbar(unsigned* bar, int grp, int idx) {
    __threadfence();
    __syncthreads();
    if (threadIdx.x == 0) {
        unsigned old = __hip_atomic_fetch_add(&bar[grp], 1u,
                           __ATOMIC_ACQ_REL, __HIP_MEMORY_SCOPE_AGENT);
        if (old == (unsigned)(idx * 16) - 1u)          // last of my 16-block group
            __hip_atomic_fetch_add(&bar[32], 1u,
                __ATOMIC_ACQ_REL, __HIP_MEMORY_SCOPE_AGENT);
        long spin = 0;
        while (__hip_atomic_load(&bar[32], __ATOMIC_ACQUIRE,
                                 __HIP_MEMORY_SCOPE_AGENT) < (unsigned)(idx * 32)) {
            __builtin_amdgcn_s_sleep(2);
            if (++spin > 20000000L) break;             // paranoia: never hang
        }
    }
    __syncthreads();
    __threadfence();
}

__device__ __forceinline__ void dec8(const float4& p, float* f) {
    const __half2* h = (const __half2*)&p;
    float2 t0 = __half22float2(h[0]);
    float2 t1 = __half22float2(h[1]);
    float2 t2 = __half22float2(h[2]);
    float2 t3 = __half22float2(h[3]);
    f[0] = t0.x; f[1] = t0.y; f[2] = t1.x; f[3] = t1.y;
    f[4] = t2.x; f[5] = t2.y; f[6] = t3.x; f[7] = t3.y;
}

__global__ __launch_bounds__(256, 2) void lanczos_persist(const float* __restrict__ A,
                                                          float* __restrict__ ws,
                                                          float* __restrict__ out) {
    float* vbuf[3] = {ws, ws + 4096, ws + 8192};
    float* slots = ws + 12288;
    float* su = ws + 12544;
    unsigned* bar = (unsigned*)(ws + 20736);
    float* n2part = ws + 20800;
    float* partials = ws + 24576;
    __half* Ah = (__half*)((char*)ws + (size_t)16 * 1024 * 1024);

    const int b = blockIdx.x, tid = threadIdx.x;
    const int lane = tid & 63, wv = tid >> 6;
    const int cA = tid * 8, cB = 2048 + tid * 8;
    const int grp = b >> 4;

    __shared__ float dgrid[4][BATCH];
    __shared__ float s_lds[BATCH];
    __shared__ float red4[4];
    __shared__ float col8[8];

    // ---- one-time: convert MY 16-row slice fp32 -> fp16 into ws ----
    {
        const float4* src = (const float4*)A + (size_t)b * (RPB * NCOLS / 4);
        float2* dst = (float2*)(Ah + (size_t)b * RPB * NCOLS);
        for (int i = tid; i < RPB * NCOLS / 4; i += 256) {
            float4 f = src[i];
            union { float2 f2; __half2 h2[2]; } u;
            u.h2[0] = __floats2half2_rn(f.x, f.y);
            u.h2[1] = __floats2half2_rn(f.z, f.w);
            dst[i] = u.f2;
        }
    }
    __syncthreads();   // slice written before my own dots read it

    float norm2_prev = 1.f, norm2_cur = 1.f;
    int bidx = 0;

    for (int j = 1; j <= T_STEPS; ++j) {
        float* rc = vbuf[j % 3];
        float* rp = vbuf[(j + 2) % 3];
        float* rn = vbuf[(j + 1) % 3];

        // ---- norm2_j: sum of n2part (identical order in every block) ----
        if (j == 1) {
            norm2_cur = 1.f;
        } else {
            float nn = (tid < 256) ? n2part[tid] + n2part[tid + 256] : 0.f;
#pragma unroll
            for (int off = 32; off; off >>= 1) nn += __shfl_xor(nn, off);
            __syncthreads();
            if (lane == 0) red4[wv] = nn;
            __syncthreads();
            norm2_cur = red4[0] + red4[1] + red4[2] + red4[3];
        }
        float inv = rsqrtf(fmaxf(norm2_cur, 1e-30f));
        if (b == 0 && tid == 0) slots[64 + j] = norm2_cur;  // for Sturm

        // ---- v = rc * inv (my 16 cols) ----
        float vA[8], vB[8];
        {
            const float4* ra = (const float4*)(rc + cA);
            float4 x = ra[0], y = ra[1];
            vA[0]=x.x*inv; vA[1]=x.y*inv; vA[2]=x.z*inv; vA[3]=x.w*inv;
            vA[4]=y.x*inv; vA[5]=y.y*inv; vA[6]=y.z*inv; vA[7]=y.w*inv;
            const float4* rb = (const float4*)(rc + cB);
            float4 z = rb[0], w = rb[1];
            vB[0]=z.x*inv; vB[1]=z.y*inv; vB[2]=z.z*inv; vB[3]=z.w*inv;
            vB[4]=w.x*inv; vB[5]=w.y*inv; vB[6]=w.z*inv; vB[7]=w.w*inv;
        }

        // ---- dots + w-accumulate, 4 rows per batch (A slice stays in L2) ----
        float wacc[16];
#pragma unroll
        for (int i = 0; i < 16; ++i) wacc[i] = 0.f;
        const __half* sl = Ah + (size_t)b * RPB * NCOLS;

#pragma unroll 1
        for (int batch = 0; batch < RPB / BATCH; ++batch) {
            float4 alo[BATCH], ahi[BATCH];
#pragma unroll
            for (int r = 0; r < BATCH; ++r) {
                const __half* rowp = sl + (size_t)(batch * BATCH + r) * NCOLS;
                alo[r] = *(const float4*)(rowp + cA);
                ahi[r] = *(const float4*)(rowp + cB);
            }
#pragma unroll
            for (int r = 0; r < BATCH; ++r) {
                float f[8];
                dec8(alo[r], f);
                float sp = f[0]*vA[0]+f[1]*vA[1]+f[2]*vA[2]+f[3]*vA[3]
                         + f[4]*vA[4]+f[5]*vA[5]+f[6]*vA[6]+f[7]*vA[7];
                dec8(ahi[r], f);
                sp += f[0]*vB[0]+f[1]*vB[1]+f[2]*vB[2]+f[3]*vB[3]
                    + f[4]*vB[4]+f[5]*vB[5]+f[6]*vB[6]+f[7]*vB[7];
#pragma unroll
                for (int off = 32; off; off >>= 1) sp += __shfl_xor(sp, off);
                if (lane == 0) dgrid[wv][r] = sp;
            }
            __syncthreads();
            if (tid < BATCH) {
                float s = dgrid[0][tid] + dgrid[1][tid] + dgrid[2][tid] + dgrid[3][tid];
                s_lds[tid] = s;
                su[b * RPB + batch * BATCH + tid] = s;
            }
            __syncthreads();
#pragma unroll
            for (int r = 0; r < BATCH; ++r) {
                float s = s_lds[r];
                float f[8];
                dec8(alo[r], f);
                wacc[0]+=s*f[0]; wacc[1]+=s*f[1]; wacc[2]+=s*f[2]; wacc[3]+=s*f[3];
                wacc[4]+=s*f[4]; wacc[5]+=s*f[5]; wacc[6]+=s*f[6]; wacc[7]+=s*f[7];
                dec8(ahi[r], f);
                wacc[8]+=s*f[0]; wacc[9]+=s*f[1]; wacc[10]+=s*f[2]; wacc[11]+=s*f[3];
                wacc[12]+=s*f[4]; wacc[13]+=s*f[5]; wacc[14]+=s*f[6]; wacc[15]+=s*f[7];
            }
            __syncthreads();   // protect dgrid/s_lds for next batch
        }
        {
            float* pb_ = partials + (size_t)b * NCOLS;
            float4* w4 = (float4*)(pb_ + cA);
            w4[0] = make_float4(wacc[0], wacc[1], wacc[2], wacc[3]);
            w4[1] = make_float4(wacc[4], wacc[5], wacc[6], wacc[7]);
            float4* w5 = (float4*)(pb_ + cB);
            w5[0] = make_float4(wacc[8], wacc[9], wacc[10], wacc[11]);
            w5[1] = make_float4(wacc[12], wacc[13], wacc[14], wacc[15]);
        }
        ++bidx; gbar(bar, grp, bidx);          // barrier A: su + partials visible

        if (j == T_STEPS) break;

        // ---- phase 2: alpha (redundant), col-reduce + recurrence ----
        float aa = 0.f;
#pragma unroll
        for (int k = 0; k < 32; ++k) { float s = su[tid + 256 * k]; aa += s * s; }
#pragma unroll
        for (int off = 32; off; off >>= 1) aa += __shfl_xor(aa, off);
        if (lane == 0) red4[wv] = aa;
        __syncthreads();
        float alpha = red4[0] + red4[1] + red4[2] + red4[3];
        if (b == 0 && tid == 0) slots[j] = alpha;   // for Sturm

        int col = b * 8 + (tid >> 5);
        int g0 = tid & 31;
        float wsum = 0.f;
#pragma unroll
        for (int k = 0; k < 16; ++k)
            wsum += partials[(size_t)(g0 + 32 * k) * NCOLS + col];
#pragma unroll
        for (int off = 16; off; off >>= 1) wsum += __shfl_xor(wsum, off);
        if (g0 == 0) {
            float cbv = sqrtf(norm2_cur / fmaxf(norm2_prev, 1e-30f));
            float rv = wsum - alpha * inv * rc[col] - cbv * rp[col];
            rn[col] = rv;
            col8[tid >> 5] = rv * rv;
        }
        __syncthreads();
        if (tid == 0) {
            float s8 = 0.f;
#pragma unroll
            for (int q = 0; q < 8; ++q) s8 += col8[q];
            n2part[b] = s8;
        }
        norm2_prev = norm2_cur;
        ++bidx; gbar(bar, grp, bidx);          // barrier B: rn + n2part visible
    }

    // ---- epilogue: block 0 computes alpha_T + Sturm bisection ----
    if (b == 0) {
        float aa = 0.f;
#pragma unroll
        for (int k = 0; k < 32; ++k) { float s = su[tid + 256 * k]; aa += s * s; }
#pragma unroll
        for (int off = 32; off; off >>= 1) aa += __shfl_xor(aa, off);
        __syncthreads();
        if (lane == 0) red4[wv] = aa;
        __syncthreads();
        if (tid == 0) slots[T_STEPS] = red4[0] + red4[1] + red4[2] + red4[3];
        __syncthreads();
        __shared__ float d_s[64], e2_s[64];
        if (tid < 64) {
            d_s[tid] = (tid < T_STEPS) ? slots[1 + tid] : 0.f;
            e2_s[tid] = (tid < T_STEPS - 1) ? slots[64 + tid + 2] : 0.f;
        }
        __syncthreads();
        if (tid < 64) {
            int ln = tid;
            float e_here = sqrtf(e2_s[ln]);
            float e_prev = (ln > 0) ? sqrtf(e2_s[ln - 1]) : 0.f;
            float d = d_s[ln];
            float gersh = (ln < T_STEPS) ? d + e_here + e_prev : 0.f;
            float dmax = (ln < T_STEPS) ? d : 0.f;
#pragma unroll
            for (int off = 32; off; off >>= 1) {
                gersh = fmaxf(gersh, __shfl_xor(gersh, off));
                dmax = fmaxf(dmax, __shfl_xor(dmax, off));
            }
            float lo = dmax, hi = gersh + 1e-3f;
            for (int round = 0; round < 3; ++round) {
                float stepw = (hi - lo) * (1.f / 64.f);
                float x = lo + stepw * (ln + 1);
                double qv = 1.0;
                int cnt = 0;
                for (int i = 0; i < T_STEPS; ++i) {
                    double qi = (double)d_s[i] - (double)x -
                                ((i > 0) ? (double)e2_s[i - 1] / qv : 0.0);
                    if (fabs(qi) < 1e-300) qi = -1e-300;
                    cnt += (qi < 0.0);
                    qv = qi;
                }
                unsigned long long m = __ballot(cnt < T_STEPS);
                if (m) {
                    int hbit = 63 - __clzll(m);
                    lo = lo + stepw * (hbit + 1);
                    hi = lo + stepw;
                } else {
                    hi = lo + stepw;
                }
            }
            if (ln == 0) out[0] = 0.5f * (lo + hi);
        }
    }
}

extern "C" void kernel_launch(void* const* d_in, const int* in_sizes, int n_in,
                              void* d_out, int out_size, void* d_ws, size_t ws_size,
                              hipStream_t stream) {
    const float* A = (const float*)d_in[0];
    float* out = (float*)d_out;
    float* ws = (float*)d_ws;

    init_kernel<<<16, 256, 0, stream>>>(ws);
    lanczos_persist<<<GRID, 256, 0, stream>>>(A, ws, out);
}

// Round 8
// 1533.301 us; speedup vs baseline: 2.9453x; 2.9453x over previous
//
#include <hip/hip_runtime.h>
#include <hip/hip_fp16.h>
#include <math.h>

// BatchSpectralLoss: out = lambda_max(A^T A), A = 8192x4096 fp32 (k==1).
// Multi-launch Lanczos (T=14), fp16 A copy in ws (read from L3 each step).
// Per step: bmv (fused u=Av dots + w-partials, A read ONCE from regs burst)
// then red (sum partials + alpha + Lanczos recurrence). NO contended atomics:
// alpha redundantly reduced per red-block from su[8192]; norm2 redundantly
// reduced per bmv-block from rc. Sturm bisection solves the tridiagonal.
//
// ws floats: vb0@0 vb1@4096 vb2@8192 | slots@12288(128) | su@12416(8192)
//   small-path partials@24576 (512x4096)
// bytes:  Ah(fp16)@16MiB (64MiB) | big-path partials@80MiB (16MiB)

#define NROWS 8192
#define NCOLS 4096
#define T_STEPS 14

__global__ __launch_bounds__(256) void init_kernel(float* __restrict__ ws) {
    int i = blockIdx.x * 256 + threadIdx.x;   // 0..4095
    unsigned h = (unsigned)i * 2654435761u;
    h ^= h >> 16; h *= 2246822519u; h ^= h >> 13;
    ws[4096 + i] = (h & 1u) ? 0.015625f : -0.015625f;  // vb1 = r1 (unit norm; j=1 reads vb[1])
    ws[i] = 0.f;                                        // vb0 = r0 = 0
    if (i < 128) ws[12288 + i] = (i == 64) ? 1.f : 0.f; // slots; norm2_0 = 1
}

__global__ __launch_bounds__(256) void convert_kernel(const float* __restrict__ A,
                                                      __half* __restrict__ Ah) {
    const float4* A4 = (const float4*)A;
    float2* O2 = (float2*)Ah;
    for (int i = blockIdx.x * 256 + threadIdx.x; i < (NROWS * NCOLS / 4); i += 2048 * 256) {
        float4 f = A4[i];
        union { float2 f2; __half2 h2[2]; } u;
        u.h2[0] = __floats2half2_rn(f.x, f.y);
        u.h2[1] = __floats2half2_rn(f.z, f.w);
        O2[i] = u.f2;
    }
}

__device__ __forceinline__ void dec8(const float4& p, float* f) {
    const __half2* h = (const __half2*)&p;
    float2 t0 = __half22float2(h[0]);
    float2 t1 = __half22float2(h[1]);
    float2 t2 = __half22float2(h[2]);
    float2 t3 = __half22float2(h[3]);
    f[0] = t0.x; f[1] = t0.y; f[2] = t1.x; f[3] = t1.y;
    f[4] = t2.x; f[5] = t2.y; f[6] = t3.x; f[7] = t3.y;
}

// Fused B-matvec. Block owns RPB rows; thread owns 16 cols (8+8 split).
// Computes block-redundant norm2 (identical fp order in every block), v,
// per-row dots s_r (-> su[row]), and register w-partials -> partials[b].
template <int RPB>
__global__ __launch_bounds__(256, 4) void bmv(const __half* __restrict__ Ah,
                                              const float* __restrict__ rc,
                                              float* __restrict__ partials,
                                              float* __restrict__ su,
                                              float* __restrict__ slots,
                                              int j) {
    __shared__ float dgrid[4][8];
    __shared__ float s_lds[8];
    __shared__ float red4[4];
    const int tid = threadIdx.x, lane = tid & 63, wv = tid >> 6;
    const int b = blockIdx.x;
    const int cA = tid * 8, cB = 2048 + tid * 8;

    // ---- v-slice + block-redundant norm2 ----
    float vA[8], vB[8];
    {
        const float4* ra = (const float4*)(rc + cA);
        float4 x = ra[0], y = ra[1];
        const float4* rb = (const float4*)(rc + cB);
        float4 z = rb[0], w = rb[1];
        vA[0]=x.x; vA[1]=x.y; vA[2]=x.z; vA[3]=x.w;
        vA[4]=y.x; vA[5]=y.y; vA[6]=y.z; vA[7]=y.w;
        vB[0]=z.x; vB[1]=z.y; vB[2]=z.z; vB[3]=z.w;
        vB[4]=w.x; vB[5]=w.y; vB[6]=w.z; vB[7]=w.w;
    }
    float nn = 0.f;
#pragma unroll
    for (int i = 0; i < 8; ++i) nn += vA[i] * vA[i] + vB[i] * vB[i];
#pragma unroll
    for (int off = 32; off; off >>= 1) nn += __shfl_xor(nn, off);
    if (lane == 0) red4[wv] = nn;
    __syncthreads();
    float norm2 = red4[0] + red4[1] + red4[2] + red4[3];
    if (b == 0 && tid == 0) slots[64 + j] = norm2;
    float inv = rsqrtf(fmaxf(norm2, 1e-30f));
#pragma unroll
    for (int i = 0; i < 8; ++i) { vA[i] *= inv; vB[i] *= inv; }

    float wacc[16];
#pragma unroll
    for (int i = 0; i < 16; ++i) wacc[i] = 0.f;
    const __half* sl = Ah + (size_t)b * RPB * NCOLS;

#pragma unroll 1
    for (int batch = 0; batch < RPB / 8; ++batch) {
        float4 alo[8], ahi[8];
#pragma unroll
        for (int r = 0; r < 8; ++r) {
            const __half* rowp = sl + (size_t)(batch * 8 + r) * NCOLS;
            alo[r] = *(const float4*)(rowp + cA);
            ahi[r] = *(const float4*)(rowp + cB);
        }
        float sp[8];
#pragma unroll
        for (int r = 0; r < 8; ++r) {
            float f[8];
            dec8(alo[r], f);
            float s = f[0]*vA[0]+f[1]*vA[1]+f[2]*vA[2]+f[3]*vA[3]
                    + f[4]*vA[4]+f[5]*vA[5]+f[6]*vA[6]+f[7]*vA[7];
            dec8(ahi[r], f);
            s += f[0]*vB[0]+f[1]*vB[1]+f[2]*vB[2]+f[3]*vB[3]
               + f[4]*vB[4]+f[5]*vB[5]+f[6]*vB[6]+f[7]*vB[7];
            sp[r] = s;
        }
#pragma unroll
        for (int r = 0; r < 8; ++r) {
#pragma unroll
            for (int off = 32; off; off >>= 1) sp[r] += __shfl_xor(sp[r], off);
        }
        if (batch) __syncthreads();          // protect dgrid/s_lds reuse
        if (lane == 0) {
#pragma unroll
            for (int r = 0; r < 8; ++r) dgrid[wv][r] = sp[r];
        }
        __syncthreads();
        if (tid < 8) {
            float s = dgrid[0][tid] + dgrid[1][tid] + dgrid[2][tid] + dgrid[3][tid];
            s_lds[tid] = s;
            su[b * RPB + batch * 8 + tid] = s;
        }
        __syncthreads();
#pragma unroll
        for (int r = 0; r < 8; ++r) {
            float s = s_lds[r];
            float f[8];
            dec8(alo[r], f);
            wacc[0]+=s*f[0]; wacc[1]+=s*f[1]; wacc[2]+=s*f[2]; wacc[3]+=s*f[3];
            wacc[4]+=s*f[4]; wacc[5]+=s*f[5]; wacc[6]+=s*f[6]; wacc[7]+=s*f[7];
            dec8(ahi[r], f);
            wacc[8]+=s*f[0]; wacc[9]+=s*f[1]; wacc[10]+=s*f[2]; wacc[11]+=s*f[3];
            wacc[12]+=s*f[4]; wacc[13]+=s*f[5]; wacc[14]+=s*f[6]; wacc[15]+=s*f[7];
        }
    }
    float* pb_ = partials + (size_t)b * NCOLS;
    float4* w4 = (float4*)(pb_ + cA);
    w4[0] = make_float4(wacc[0], wacc[1], wacc[2], wacc[3]);
    w4[1] = make_float4(wacc[4], wacc[5], wacc[6], wacc[7]);
    float4* w5 = (float4*)(pb_ + cB);
    w5[0] = make_float4(wacc[8], wacc[9], wacc[10], wacc[11]);
    w5[1] = make_float4(wacc[12], wacc[13], wacc[14], wacc[15]);
}

// Sum NP partials per column + alpha (redundant from su) + recurrence.
// 64 blocks x 256 thr; block handles 64 cols; wave wv sums a quarter of NP.
__global__ __launch_bounds__(256) void red_kernel(const float* __restrict__ partials,
                                                  const float* __restrict__ su,
                                                  float* __restrict__ wt,
                                                  const float* __restrict__ rc,
                                                  const float* __restrict__ rp,
                                                  float* __restrict__ slots,
                                                  int j, int NP) {
    __shared__ float redw[4][64];
    __shared__ float red4[4];
    int tid = threadIdx.x, lane = tid & 63, wv = tid >> 6;
    int col = blockIdx.x * 64 + lane;
    float aa = 0.f;
    for (int k = tid; k < NROWS; k += 256) { float s = su[k]; aa += s * s; }
#pragma unroll
    for (int off = 32; off; off >>= 1) aa += __shfl_xor(aa, off);
    if (lane == 0) red4[wv] = aa;
    float wsum = 0.f;
    int q = NP >> 2;
    const float* p0 = partials + (size_t)(wv * q) * NCOLS + col;
    for (int g = 0; g < q; ++g) wsum += p0[(size_t)g * NCOLS];
    redw[wv][lane] = wsum;
    __syncthreads();
    if (tid < 64) {
        float alpha = red4[0] + red4[1] + red4[2] + red4[3];
        if (blockIdx.x == 0 && tid == 0) slots[j] = alpha;
        int c = blockIdx.x * 64 + tid;
        float w = redw[0][tid] + redw[1][tid] + redw[2][tid] + redw[3][tid];
        float n2j = fmaxf(slots[64 + j], 1e-30f);
        float n2m = fmaxf(slots[64 + j - 1], 1e-30f);
        float invj = rsqrtf(n2j);
        float cb = sqrtf(n2j / n2m);               // beta_{j-1}/||r_{j-1}||
        wt[c] = w - alpha * invj * rc[c] - cb * rp[c];
    }
}

// Sturm bisection on the T x T tridiagonal; alpha_T reduced from su here.
__global__ void solve_kernel(const float* __restrict__ slots,
                             const float* __restrict__ su,
                             float* __restrict__ out, int t) {
    int lane = threadIdx.x;   // 64 threads
    float aa = 0.f;
    for (int k = lane; k < NROWS; k += 64) { float s = su[k]; aa += s * s; }
#pragma unroll
    for (int off = 32; off; off >>= 1) aa += __shfl_xor(aa, off);
    float alphaT = aa;        // identical in all lanes after butterfly
    __shared__ float d_s[64], e2_s[64];
    d_s[lane] = (lane < t - 1) ? slots[1 + lane] : ((lane == t - 1) ? alphaT : 0.f);
    e2_s[lane] = (lane < t - 1) ? slots[64 + lane + 2] : 0.f;
    __syncthreads();
    float e_here = sqrtf(e2_s[lane]);
    float e_prev = (lane > 0) ? sqrtf(e2_s[lane - 1]) : 0.f;
    float d = d_s[lane];
    float gersh = (lane < t) ? d + e_here + e_prev : 0.f;
    float dmax = (lane < t) ? d : 0.f;
#pragma unroll
    for (int off = 32; off; off >>= 1) {
        gersh = fmaxf(gersh, __shfl_xor(gersh, off));
        dmax = fmaxf(dmax, __shfl_xor(dmax, off));
    }
    float lo = dmax, hi = gersh + 1e-3f;
    for (int round = 0; round < 3; ++round) {
        float stepw = (hi - lo) * (1.f / 64.f);
        float x = lo + stepw * (lane + 1);
        double qv = 1.0;
        int cnt = 0;
        for (int i = 0; i < t; ++i) {
            double qi = (double)d_s[i] - (double)x -
                        ((i > 0) ? (double)e2_s[i - 1] / qv : 0.0);
            if (fabs(qi) < 1e-300) qi = -1e-300;
            cnt += (qi < 0.0);
            qv = qi;
        }
        unsigned long long m = __ballot(cnt < t);
        if (m) {
            int hbit = 63 - __clzll(m);
            lo = lo + stepw * (hbit + 1);
            hi = lo + stepw;
        } else {
            hi = lo + stepw;
        }
    }
    if (lane == 0) out[0] = 0.5f * (lo + hi);
}

extern "C" void kernel_launch(void* const* d_in, const int* in_sizes, int n_in,
                              void* d_out, int out_size, void* d_ws, size_t ws_size,
                              hipStream_t stream) {
    const float* A = (const float*)d_in[0];
    float* out = (float*)d_out;
    float* ws = (float*)d_ws;
    float* vb[3] = {ws, ws + 4096, ws + 8192};
    float* slots = ws + 12288;
    float* su = ws + 12416;
    __half* Ah = (__half*)((char*)d_ws + (size_t)16 * 1024 * 1024);

    // big path: partials (1024x4096 fp32 = 16 MiB) after Ah at 80 MiB
    const size_t MiB = 1024 * 1024;
    bool big = ws_size >= 97 * MiB;
    int NP = big ? 1024 : 512;
    float* partials = big ? (float*)((char*)d_ws + 80 * MiB) : (ws + 24576);

    init_kernel<<<16, 256, 0, stream>>>(ws);
    convert_kernel<<<2048, 256, 0, stream>>>(A, Ah);

    const int T = T_STEPS;
    for (int j = 1; j <= T; ++j) {
        float* rc = vb[j % 3];          // r_j     (init put r1 in vb[1])
        float* rp = vb[(j + 2) % 3];    // r_{j-1} (vb[0] = zeros at j=1)
        float* wt = vb[(j + 1) % 3];    // -> r_{j+1}
        if (big)
            bmv<8><<<1024, 256, 0, stream>>>(Ah, rc, partials, su, slots, j);
        else
            bmv<16><<<512, 256, 0, stream>>>(Ah, rc, partials, su, slots, j);
        if (j < T)
            red_kernel<<<64, 256, 0, stream>>>(partials, su, wt, rc, rp, slots, j, NP);
    }
    solve_kernel<<<1, 64, 0, stream>>>(slots, su, out, T);
}